// Round 8
// baseline (878.111 us; speedup 1.0000x reference)
//
#include <hip/hip_runtime.h>
#include <math.h>

#define N_NODES 128000
#define B_G 256
#define NPG 500
#define F_IN 128
#define D_LAT 32
#define K_TOP 30
#define L_LAYERS 3
#define E_EDGES 2048000

#define BSH 7                      // bucket = dst >> 7
#define NB (N_NODES >> BSH)        // 1000 buckets x 128 nodes
#define CHUNK 8192
#define CBLOCKS (E_EDGES / CHUNK)  // 250

// ---------------------------------------------------------------------------
// Fold the concat weights once: We = Wa0+Wa2, Wn = Wa1+Wa2 (per layer).
// ---------------------------------------------------------------------------
__global__ __launch_bounds__(256) void k_foldw(
    const float* __restrict__ W1a, float* __restrict__ wfold)
{
    const int l = blockIdx.x, t = threadIdx.x;
    const float* base = W1a + (size_t)l * 3 * D_LAT * D_LAT;
    float* o = wfold + (size_t)l * 2 * D_LAT * D_LAT;
    for (int i = t; i < D_LAT * D_LAT; i += 256) {
        const float wc = base[2 * D_LAT * D_LAT + i];
        o[i] = base[i] + wc;                                  // We
        o[D_LAT * D_LAT + i] = base[D_LAT * D_LAT + i] + wc;  // Wn
    }
}

// ---------------------------------------------------------------------------
// Kernel 1: ego = relu(X @ w0a + b0a) @ w0b + b0b ;  out = alpha[0] * ego
// Thread = row, scalar-path weights (wave-uniform addresses). Unchanged.
// ---------------------------------------------------------------------------
__global__ __launch_bounds__(256) void k_mlp0(
    const float* __restrict__ X, const float* __restrict__ w0a,
    const float* __restrict__ b0a, const float* __restrict__ w0b,
    const float* __restrict__ b0b, const float* __restrict__ alpha,
    float* __restrict__ ego, float* __restrict__ outb)
{
    const size_t row = (size_t)blockIdx.x * 256 + threadIdx.x;
    const float4* xp = (const float4*)(X + row * F_IN);
    const float a0 = alpha[0];

    float acc[D_LAT];
    #pragma unroll
    for (int j = 0; j < D_LAT; ++j) acc[j] = b0a[j];

    #pragma unroll 1
    for (int c = 0; c < F_IN / 16; ++c) {
        const float4 x0 = xp[c * 4 + 0], x1 = xp[c * 4 + 1];
        const float4 x2 = xp[c * 4 + 2], x3 = xp[c * 4 + 3];
        const float xs[16] = {x0.x, x0.y, x0.z, x0.w, x1.x, x1.y, x1.z, x1.w,
                              x2.x, x2.y, x2.z, x2.w, x3.x, x3.y, x3.z, x3.w};
        #pragma unroll
        for (int ff = 0; ff < 16; ++ff) {
            const float xf = xs[ff];
            const float* wr = w0a + (c * 16 + ff) * D_LAT;   // uniform addr
            #pragma unroll
            for (int j = 0; j < D_LAT; ++j)
                acc[j] = fmaf(xf, wr[j], acc[j]);
        }
    }

    #pragma unroll
    for (int j = 0; j < D_LAT; ++j) acc[j] = fmaxf(acc[j], 0.f);

    float acc2[D_LAT];
    #pragma unroll
    for (int j = 0; j < D_LAT; ++j) acc2[j] = b0b[j];
    #pragma unroll 1
    for (int c = 0; c < D_LAT / 8; ++c) {
        #pragma unroll
        for (int kk = 0; kk < 8; ++kk) {
            const float h = acc[c * 8 + kk];
            const float* wr = w0b + (c * 8 + kk) * D_LAT;    // uniform addr
            #pragma unroll
            for (int j = 0; j < D_LAT; ++j)
                acc2[j] = fmaf(h, wr[j], acc2[j]);
        }
    }

    float4* eo = (float4*)(ego + row * D_LAT);
    float4* oo = (float4*)(outb + row * D_LAT);
    #pragma unroll
    for (int q = 0; q < D_LAT / 4; ++q) {
        eo[q] = make_float4(acc2[q*4], acc2[q*4+1], acc2[q*4+2], acc2[q*4+3]);
        oo[q] = make_float4(a0*acc2[q*4], a0*acc2[q*4+1],
                            a0*acc2[q*4+2], a0*acc2[q*4+3]);
    }
}

// ---------------------------------------------------------------------------
// Radix CSR build (unchanged)
// ---------------------------------------------------------------------------
__global__ __launch_bounds__(256) void k_bcount(
    const int* __restrict__ edst, int* __restrict__ ghist)
{
    __shared__ int cnt[NB];
    const int t = threadIdx.x;
    for (int i = t; i < NB; i += 256) cnt[i] = 0;
    __syncthreads();
    const int ebase = blockIdx.x * CHUNK;
    for (int i = 0; i < CHUNK / 256; ++i)
        atomicAdd(&cnt[edst[ebase + i * 256 + t] >> BSH], 1);
    __syncthreads();
    for (int i = t; i < NB; i += 256)
        if (cnt[i]) atomicAdd(&ghist[i], cnt[i]);
}

__global__ __launch_bounds__(1024) void k_bscan(
    const int* __restrict__ ghist, int* __restrict__ gbase,
    int* __restrict__ gcursor)
{
    __shared__ int buf[2][1024];
    const int t = threadIdx.x;
    const int v = (t < NB) ? ghist[t] : 0;
    buf[0][t] = v;
    __syncthreads();
    int cur = 0;
    for (int o = 1; o < 1024; o <<= 1) {
        int x = buf[cur][t];
        if (t >= o) x += buf[cur][t - o];
        buf[cur ^ 1][t] = x;
        cur ^= 1;
        __syncthreads();
    }
    if (t < NB) { const int e = buf[cur][t] - v; gbase[t] = e; gcursor[t] = e; }
    if (t == 0) gbase[NB] = E_EDGES;
}

__global__ __launch_bounds__(256) void k_bscatter(
    const int* __restrict__ esrc, const int* __restrict__ edst,
    int* __restrict__ gcursor, int* __restrict__ packed)
{
    __shared__ int cnt[NB];
    __shared__ int sbase[NB];
    const int t = threadIdx.x;
    for (int i = t; i < NB; i += 256) cnt[i] = 0;
    __syncthreads();
    const int ebase = blockIdx.x * CHUNK;
    for (int i = 0; i < CHUNK / 256; ++i)
        atomicAdd(&cnt[edst[ebase + i * 256 + t] >> BSH], 1);
    __syncthreads();
    for (int i = t; i < NB; i += 256) {
        const int c = cnt[i];
        sbase[i] = c ? atomicAdd(&gcursor[i], c) : 0;
        cnt[i] = 0;
    }
    __syncthreads();
    for (int i = 0; i < CHUNK / 256; ++i) {
        const int e = ebase + i * 256 + t;
        const int d = edst[e], s = esrc[e];
        const int b = d >> BSH;
        const int r = atomicAdd(&cnt[b], 1);
        packed[sbase[b] + r] = (s << BSH) | (d & ((1 << BSH) - 1));
    }
}

__global__ __launch_bounds__(256) void k_bcsr(
    const int* __restrict__ gbase, const int* __restrict__ packed,
    int* __restrict__ off, int* __restrict__ srcidx)
{
    __shared__ int cnt[128];
    __shared__ int scn[128];
    __shared__ int sbuf[4096];
    const int b = blockIdx.x, t = threadIdx.x;
    const int s0 = gbase[b], s1 = gbase[b + 1], m = s1 - s0;

    if (t < 128) cnt[t] = 0;
    __syncthreads();
    for (int i = t; i < m; i += 256)
        atomicAdd(&cnt[packed[s0 + i] & 127], 1);
    __syncthreads();
    if (t == 0) {
        int a = 0;
        for (int k = 0; k < 128; ++k) { scn[k] = a; a += cnt[k]; }
    }
    __syncthreads();
    if (t < 128) { off[(b << BSH) + t] = s0 + scn[t]; cnt[t] = 0; }
    if (b == 0 && t == 0) off[N_NODES] = E_EDGES;
    __syncthreads();
    for (int i = t; i < m; i += 256) {
        const int p = packed[s0 + i];
        const int dl = p & 127;
        const int r = atomicAdd(&cnt[dl], 1);
        sbuf[scn[dl] + r] = p >> BSH;
    }
    __syncthreads();
    for (int i = t; i < m; i += 256) srcidx[s0 + i] = sbuf[i];
}

// ---------------------------------------------------------------------------
// Fused layer, 2 threads per node. Lanes (2n,2n+1) each gather one 64-B half
// of every neighbor row (halved latency chain, doubled wave count), exchange
// halves via shfl_xor, then both lanes run the full MLP redundantly with
// wave-uniform (scalar-path) weight reads. Each lane writes its own half.
// All half-dependent accesses are constant-index + select (no scratch).
// ---------------------------------------------------------------------------
__global__ __launch_bounds__(256) void k_layer(
    const float* __restrict__ in, const int* __restrict__ off,
    const int* __restrict__ srcidx, const float* __restrict__ wfold_l,
    const float* __restrict__ W1b_l, const float* __restrict__ B1a_l,
    const float* __restrict__ B1b_l, const float* __restrict__ alpha,
    const int l, float* __restrict__ out, float* __restrict__ outb)
{
    const int gtid = blockIdx.x * 256 + threadIdx.x;
    const size_t n = (size_t)(gtid >> 1);
    const int half = gtid & 1;
    const int s0 = off[n], s1 = off[n + 1];
    const float al = alpha[l + 1];

    const float* inh = in + half * 16;   // my 16-channel slice base

    // gather my half of the neighbor sum (unroll 2 -> 8 b128 loads in flight)
    float4 g0 = {0,0,0,0}, g1 = {0,0,0,0}, g2 = {0,0,0,0}, g3 = {0,0,0,0};
    int i = s0;
    for (; i + 2 <= s1; i += 2) {
        const int sa = srcidx[i], sb = srcidx[i + 1];
        const float4* pa = (const float4*)(inh + (size_t)sa * D_LAT);
        const float4* pb = (const float4*)(inh + (size_t)sb * D_LAT);
        const float4 a0 = pa[0], a1 = pa[1], a2 = pa[2], a3 = pa[3];
        const float4 b0 = pb[0], b1 = pb[1], b2 = pb[2], b3 = pb[3];
        g0.x += a0.x + b0.x; g0.y += a0.y + b0.y; g0.z += a0.z + b0.z; g0.w += a0.w + b0.w;
        g1.x += a1.x + b1.x; g1.y += a1.y + b1.y; g1.z += a1.z + b1.z; g1.w += a1.w + b1.w;
        g2.x += a2.x + b2.x; g2.y += a2.y + b2.y; g2.z += a2.z + b2.z; g2.w += a2.w + b2.w;
        g3.x += a3.x + b3.x; g3.y += a3.y + b3.y; g3.z += a3.z + b3.z; g3.w += a3.w + b3.w;
    }
    if (i < s1) {
        const int sa = srcidx[i];
        const float4* pa = (const float4*)(inh + (size_t)sa * D_LAT);
        const float4 a0 = pa[0], a1 = pa[1], a2 = pa[2], a3 = pa[3];
        g0.x += a0.x; g0.y += a0.y; g0.z += a0.z; g0.w += a0.w;
        g1.x += a1.x; g1.y += a1.y; g1.z += a1.z; g1.w += a1.w;
        g2.x += a2.x; g2.y += a2.y; g2.z += a2.z; g2.w += a2.w;
        g3.x += a3.x; g3.y += a3.y; g3.z += a3.z; g3.w += a3.w;
    }
    float mine[16];
    mine[0]=g0.x; mine[1]=g0.y; mine[2]=g0.z; mine[3]=g0.w;
    mine[4]=g1.x; mine[5]=g1.y; mine[6]=g1.z; mine[7]=g1.w;
    mine[8]=g2.x; mine[9]=g2.y; mine[10]=g2.z; mine[11]=g2.w;
    mine[12]=g3.x; mine[13]=g3.y; mine[14]=g3.z; mine[15]=g3.w;

    // my half of own row
    float emine[16];
    {
        const float4* ep = (const float4*)(inh + n * D_LAT);
        const float4 e0 = ep[0], e1 = ep[1], e2 = ep[2], e3 = ep[3];
        emine[0]=e0.x; emine[1]=e0.y; emine[2]=e0.z; emine[3]=e0.w;
        emine[4]=e1.x; emine[5]=e1.y; emine[6]=e1.z; emine[7]=e1.w;
        emine[8]=e2.x; emine[9]=e2.y; emine[10]=e2.z; emine[11]=e2.w;
        emine[12]=e3.x; emine[13]=e3.y; emine[14]=e3.z; emine[15]=e3.w;
    }

    // exchange halves: lane-pair partner holds the other 16 channels
    float ngs[D_LAT], eg[D_LAT];
    #pragma unroll
    for (int d = 0; d < 16; ++d) {
        const float og = __shfl_xor(mine[d], 1);
        const float oe = __shfl_xor(emine[d], 1);
        ngs[d]      = half ? og       : mine[d];
        ngs[16 + d] = half ? mine[d]  : og;
        eg[d]       = half ? oe       : emine[d];
        eg[16 + d]  = half ? emine[d] : oe;
    }

    // stage 1: ego @ We + neig @ Wn + B1a (scalar-path weights)
    float acc[D_LAT];
    #pragma unroll
    for (int j = 0; j < D_LAT; ++j) acc[j] = B1a_l[j];
    #pragma unroll 1
    for (int c = 0; c < D_LAT / 8; ++c) {
        #pragma unroll
        for (int kk = 0; kk < 8; ++kk) {
            const int k = c * 8 + kk;
            const float fe = eg[k], fn = ngs[k];
            const float* we = wfold_l + k * D_LAT;                    // uniform
            const float* wn = wfold_l + D_LAT * D_LAT + k * D_LAT;    // uniform
            #pragma unroll
            for (int j = 0; j < D_LAT; ++j)
                acc[j] = fmaf(fe, we[j], fmaf(fn, wn[j], acc[j]));
        }
    }
    #pragma unroll
    for (int j = 0; j < D_LAT; ++j) acc[j] = fmaxf(acc[j], 0.f);

    // stage 2
    float acc2[D_LAT];
    #pragma unroll
    for (int j = 0; j < D_LAT; ++j) acc2[j] = B1b_l[j];
    #pragma unroll 1
    for (int c = 0; c < D_LAT / 8; ++c) {
        #pragma unroll
        for (int kk = 0; kk < 8; ++kk) {
            const float h = acc[c * 8 + kk];
            const float* wr = W1b_l + (c * 8 + kk) * D_LAT;           // uniform
            #pragma unroll
            for (int j = 0; j < D_LAT; ++j)
                acc2[j] = fmaf(h, wr[j], acc2[j]);
        }
    }

    // write my 16-channel half (constant-index selects, coalesced lane pairs)
    float4* eo = (float4*)(out + n * D_LAT + half * 16);
    float4* oo = (float4*)(outb + n * D_LAT + half * 16);
    #pragma unroll
    for (int q = 0; q < 4; ++q) {
        const float v0 = half ? acc2[16 + q*4 + 0] : acc2[q*4 + 0];
        const float v1 = half ? acc2[16 + q*4 + 1] : acc2[q*4 + 1];
        const float v2 = half ? acc2[16 + q*4 + 2] : acc2[q*4 + 2];
        const float v3 = half ? acc2[16 + q*4 + 3] : acc2[q*4 + 3];
        const float4 prev = oo[q];
        eo[q] = make_float4(v0, v1, v2, v3);
        oo[q] = make_float4(fmaf(al, v0, prev.x), fmaf(al, v1, prev.y),
                            fmaf(al, v2, prev.z), fmaf(al, v3, prev.w));
    }
}

// ---------------------------------------------------------------------------
// Per-graph top-30 (stable ties -> smaller index) + gather + relu (unchanged)
// ---------------------------------------------------------------------------
__global__ __launch_bounds__(256) void k_topk(
    const float* __restrict__ ego, const float* __restrict__ outb,
    float* __restrict__ y)
{
    __shared__ float vals[512];
    __shared__ int topidx[K_TOP];
    __shared__ float wv[4];
    __shared__ int wi[4];

    const int g = blockIdx.x, t = threadIdx.x;
    for (int i = t; i < 512; i += 256)
        vals[i] = (i < NPG) ? ego[((size_t)g * NPG + i) * D_LAT + (D_LAT - 1)]
                            : -INFINITY;
    __syncthreads();

    for (int k = 0; k < K_TOP; ++k) {
        float v = -INFINITY; int bi = 0x7fffffff;
        for (int i = t; i < NPG; i += 256) {
            const float x = vals[i];
            if (x > v || (x == v && i < bi)) { v = x; bi = i; }
        }
        for (int off = 32; off > 0; off >>= 1) {
            const float ov = __shfl_down(v, off);
            const int   oi = __shfl_down(bi, off);
            if (ov > v || (ov == v && oi < bi)) { v = ov; bi = oi; }
        }
        if ((t & 63) == 0) { wv[t >> 6] = v; wi[t >> 6] = bi; }
        __syncthreads();
        if (t == 0) {
            for (int w = 1; w < 4; ++w)
                if (wv[w] > v || (wv[w] == v && wi[w] < bi)) { v = wv[w]; bi = wi[w]; }
            topidx[k] = bi;
            vals[bi] = -INFINITY;
        }
        __syncthreads();
    }

    for (int j = t; j < K_TOP * D_LAT; j += 256) {
        const int kk = j >> 5, d = j & 31;
        const size_t node = (size_t)g * NPG + topidx[kk];
        y[(size_t)g * (K_TOP * D_LAT) + j] = fmaxf(outb[node * D_LAT + d], 0.f);
    }
}

// ---------------------------------------------------------------------------
extern "C" void kernel_launch(void* const* d_in, const int* in_sizes, int n_in,
                              void* d_out, int out_size, void* d_ws, size_t ws_size,
                              hipStream_t stream)
{
    const float* X    = (const float*)d_in[0];
    const float* alpha= (const float*)d_in[1];
    const float* w0a  = (const float*)d_in[2];
    const float* b0a  = (const float*)d_in[3];
    const float* w0b  = (const float*)d_in[4];
    const float* b0b  = (const float*)d_in[5];
    const float* W1a  = (const float*)d_in[6];
    const float* B1a  = (const float*)d_in[7];
    const float* W1b  = (const float*)d_in[8];
    const float* B1b  = (const float*)d_in[9];
    const int* esrc   = (const int*)d_in[10];
    const int* edst   = (const int*)d_in[11];
    float* y = (float*)d_out;

    float* egoA   = (float*)d_ws;
    float* outb   = egoA + (size_t)N_NODES * D_LAT;
    float* egoB   = outb + (size_t)N_NODES * D_LAT;
    int*   packed = (int*)egoB;                              // alias: dead before layer 0
    int*   off    = (int*)(egoB + (size_t)N_NODES * D_LAT);  // N+1
    int*   srcidx = off + (N_NODES + 1);                     // E
    int*   ghist  = srcidx + E_EDGES;                        // NB
    int*   gbase  = ghist + NB;                              // NB+1
    int*   gcursor= gbase + (NB + 1);                        // NB
    float* wfold  = (float*)(gcursor + NB);                  // 3 * 2048

    k_foldw<<<L_LAYERS, 256, 0, stream>>>(W1a, wfold);

    hipMemsetAsync(ghist, 0, NB * sizeof(int), stream);
    k_bcount  <<<CBLOCKS, 256, 0, stream>>>(edst, ghist);
    k_bscan   <<<1, 1024, 0, stream>>>(ghist, gbase, gcursor);
    k_bscatter<<<CBLOCKS, 256, 0, stream>>>(esrc, edst, gcursor, packed);
    k_bcsr    <<<NB, 256, 0, stream>>>(gbase, packed, off, srcidx);

    k_mlp0<<<N_NODES / 256, 256, 0, stream>>>(X, w0a, b0a, w0b, b0b, alpha, egoA, outb);

    float* cur = egoA;
    float* nxt = egoB;
    for (int l = 0; l < L_LAYERS; ++l) {
        k_layer<<<N_NODES * 2 / 256, 256, 0, stream>>>(
            cur, off, srcidx, wfold + (size_t)l * 2 * D_LAT * D_LAT,
            W1b + (size_t)l * D_LAT * D_LAT, B1a + (size_t)l * D_LAT,
            B1b + (size_t)l * D_LAT, alpha, l, nxt, outb);
        float* tmp = cur; cur = nxt; nxt = tmp;
    }

    // after 3 layers, final ego is in `cur` (== egoB)
    k_topk<<<B_G, 256, 0, stream>>>(cur, outb, y);
}

// Round 9
// 467.868 us; speedup vs baseline: 1.8768x; 1.8768x over previous
//
#include <hip/hip_runtime.h>
#include <math.h>

#define N_NODES 128000
#define B_G 256
#define NPG 500
#define F_IN 128
#define D_LAT 32
#define K_TOP 30
#define L_LAYERS 3
#define E_EDGES 2048000

#define BSH 7                      // bucket = dst >> 7
#define NB (N_NODES >> BSH)        // 1000 buckets x 128 nodes
#define CHUNK 8192
#define CBLOCKS (E_EDGES / CHUNK)  // 250

// ---------------------------------------------------------------------------
// Fold the concat weights once: We = Wa0+Wa2, Wn = Wa1+Wa2 (per layer).
// ---------------------------------------------------------------------------
__global__ __launch_bounds__(256) void k_foldw(
    const float* __restrict__ W1a, float* __restrict__ wfold)
{
    const int l = blockIdx.x, t = threadIdx.x;
    const float* base = W1a + (size_t)l * 3 * D_LAT * D_LAT;
    float* o = wfold + (size_t)l * 2 * D_LAT * D_LAT;
    for (int i = t; i < D_LAT * D_LAT; i += 256) {
        const float wc = base[2 * D_LAT * D_LAT + i];
        o[i] = base[i] + wc;                                  // We
        o[D_LAT * D_LAT + i] = base[D_LAT * D_LAT + i] + wc;  // Wn
    }
}

// ---------------------------------------------------------------------------
// Kernel 1: ego = relu(X @ w0a + b0a) @ w0b + b0b ;  out = alpha[0] * ego
// Thread = row, scalar-path weights (wave-uniform addresses). Unchanged.
// ---------------------------------------------------------------------------
__global__ __launch_bounds__(256) void k_mlp0(
    const float* __restrict__ X, const float* __restrict__ w0a,
    const float* __restrict__ b0a, const float* __restrict__ w0b,
    const float* __restrict__ b0b, const float* __restrict__ alpha,
    float* __restrict__ ego, float* __restrict__ outb)
{
    const size_t row = (size_t)blockIdx.x * 256 + threadIdx.x;
    const float4* xp = (const float4*)(X + row * F_IN);
    const float a0 = alpha[0];

    float acc[D_LAT];
    #pragma unroll
    for (int j = 0; j < D_LAT; ++j) acc[j] = b0a[j];

    #pragma unroll 1
    for (int c = 0; c < F_IN / 16; ++c) {
        const float4 x0 = xp[c * 4 + 0], x1 = xp[c * 4 + 1];
        const float4 x2 = xp[c * 4 + 2], x3 = xp[c * 4 + 3];
        const float xs[16] = {x0.x, x0.y, x0.z, x0.w, x1.x, x1.y, x1.z, x1.w,
                              x2.x, x2.y, x2.z, x2.w, x3.x, x3.y, x3.z, x3.w};
        #pragma unroll
        for (int ff = 0; ff < 16; ++ff) {
            const float xf = xs[ff];
            const float* wr = w0a + (c * 16 + ff) * D_LAT;   // uniform addr
            #pragma unroll
            for (int j = 0; j < D_LAT; ++j)
                acc[j] = fmaf(xf, wr[j], acc[j]);
        }
    }

    #pragma unroll
    for (int j = 0; j < D_LAT; ++j) acc[j] = fmaxf(acc[j], 0.f);

    float acc2[D_LAT];
    #pragma unroll
    for (int j = 0; j < D_LAT; ++j) acc2[j] = b0b[j];
    #pragma unroll 1
    for (int c = 0; c < D_LAT / 8; ++c) {
        #pragma unroll
        for (int kk = 0; kk < 8; ++kk) {
            const float h = acc[c * 8 + kk];
            const float* wr = w0b + (c * 8 + kk) * D_LAT;    // uniform addr
            #pragma unroll
            for (int j = 0; j < D_LAT; ++j)
                acc2[j] = fmaf(h, wr[j], acc2[j]);
        }
    }

    float4* eo = (float4*)(ego + row * D_LAT);
    float4* oo = (float4*)(outb + row * D_LAT);
    #pragma unroll
    for (int q = 0; q < D_LAT / 4; ++q) {
        eo[q] = make_float4(acc2[q*4], acc2[q*4+1], acc2[q*4+2], acc2[q*4+3]);
        oo[q] = make_float4(a0*acc2[q*4], a0*acc2[q*4+1],
                            a0*acc2[q*4+2], a0*acc2[q*4+3]);
    }
}

// ---------------------------------------------------------------------------
// Radix CSR build (unchanged)
// ---------------------------------------------------------------------------
__global__ __launch_bounds__(256) void k_bcount(
    const int* __restrict__ edst, int* __restrict__ ghist)
{
    __shared__ int cnt[NB];
    const int t = threadIdx.x;
    for (int i = t; i < NB; i += 256) cnt[i] = 0;
    __syncthreads();
    const int ebase = blockIdx.x * CHUNK;
    for (int i = 0; i < CHUNK / 256; ++i)
        atomicAdd(&cnt[edst[ebase + i * 256 + t] >> BSH], 1);
    __syncthreads();
    for (int i = t; i < NB; i += 256)
        if (cnt[i]) atomicAdd(&ghist[i], cnt[i]);
}

__global__ __launch_bounds__(1024) void k_bscan(
    const int* __restrict__ ghist, int* __restrict__ gbase,
    int* __restrict__ gcursor)
{
    __shared__ int buf[2][1024];
    const int t = threadIdx.x;
    const int v = (t < NB) ? ghist[t] : 0;
    buf[0][t] = v;
    __syncthreads();
    int cur = 0;
    for (int o = 1; o < 1024; o <<= 1) {
        int x = buf[cur][t];
        if (t >= o) x += buf[cur][t - o];
        buf[cur ^ 1][t] = x;
        cur ^= 1;
        __syncthreads();
    }
    if (t < NB) { const int e = buf[cur][t] - v; gbase[t] = e; gcursor[t] = e; }
    if (t == 0) gbase[NB] = E_EDGES;
}

__global__ __launch_bounds__(256) void k_bscatter(
    const int* __restrict__ esrc, const int* __restrict__ edst,
    int* __restrict__ gcursor, int* __restrict__ packed)
{
    __shared__ int cnt[NB];
    __shared__ int sbase[NB];
    const int t = threadIdx.x;
    for (int i = t; i < NB; i += 256) cnt[i] = 0;
    __syncthreads();
    const int ebase = blockIdx.x * CHUNK;
    for (int i = 0; i < CHUNK / 256; ++i)
        atomicAdd(&cnt[edst[ebase + i * 256 + t] >> BSH], 1);
    __syncthreads();
    for (int i = t; i < NB; i += 256) {
        const int c = cnt[i];
        sbase[i] = c ? atomicAdd(&gcursor[i], c) : 0;
        cnt[i] = 0;
    }
    __syncthreads();
    for (int i = 0; i < CHUNK / 256; ++i) {
        const int e = ebase + i * 256 + t;
        const int d = edst[e], s = esrc[e];
        const int b = d >> BSH;
        const int r = atomicAdd(&cnt[b], 1);
        packed[sbase[b] + r] = (s << BSH) | (d & ((1 << BSH) - 1));
    }
}

__global__ __launch_bounds__(256) void k_bcsr(
    const int* __restrict__ gbase, const int* __restrict__ packed,
    int* __restrict__ off, int* __restrict__ srcidx)
{
    __shared__ int cnt[128];
    __shared__ int scn[128];
    __shared__ int sbuf[4096];
    const int b = blockIdx.x, t = threadIdx.x;
    const int s0 = gbase[b], s1 = gbase[b + 1], m = s1 - s0;

    if (t < 128) cnt[t] = 0;
    __syncthreads();
    for (int i = t; i < m; i += 256)
        atomicAdd(&cnt[packed[s0 + i] & 127], 1);
    __syncthreads();
    if (t == 0) {
        int a = 0;
        for (int k = 0; k < 128; ++k) { scn[k] = a; a += cnt[k]; }
    }
    __syncthreads();
    if (t < 128) { off[(b << BSH) + t] = s0 + scn[t]; cnt[t] = 0; }
    if (b == 0 && t == 0) off[N_NODES] = E_EDGES;
    __syncthreads();
    for (int i = t; i < m; i += 256) {
        const int p = packed[s0 + i];
        const int dl = p & 127;
        const int r = atomicAdd(&cnt[dl], 1);
        sbuf[scn[dl] + r] = p >> BSH;
    }
    __syncthreads();
    for (int i = t; i < m; i += 256) srcidx[s0 + i] = sbuf[i];
}

// ---------------------------------------------------------------------------
// Fused layer, EDGE-split: 2 threads per node; lane 2n sums even-indexed
// neighbors, lane 2n+1 odd-indexed — each reading FULL 128-B rows (round-7
// proven access shape), so per-instruction transaction efficiency is
// unchanged while wave count doubles and the serial gather chain halves.
// Partial sums combined via shfl_xor; MLP runs redundantly in both lanes
// (scalar-path weights); lane 2n writes the full ego row, lane 2n+1 the
// full outb RMW row (contiguous 128-B per-lane store streams).
// ---------------------------------------------------------------------------
__global__ __launch_bounds__(256) void k_layer(
    const float* __restrict__ in, const int* __restrict__ off,
    const int* __restrict__ srcidx, const float* __restrict__ wfold_l,
    const float* __restrict__ W1b_l, const float* __restrict__ B1a_l,
    const float* __restrict__ B1b_l, const float* __restrict__ alpha,
    const int l, float* __restrict__ out, float* __restrict__ outb)
{
    const int gtid = blockIdx.x * 256 + threadIdx.x;
    const size_t n = (size_t)(gtid >> 1);
    const int half = gtid & 1;
    const int s0 = off[n], s1 = off[n + 1];
    const float al = alpha[l + 1];

    // partial neighbor sum: neighbors s0+half, s0+half+2, ... (full rows)
    float4 ng[8];
    #pragma unroll
    for (int q = 0; q < 8; ++q) ng[q] = make_float4(0.f, 0.f, 0.f, 0.f);
    for (int i = s0 + half; i < s1; i += 2) {
        const int s = srcidx[i];
        const float4* vp = (const float4*)(in + (size_t)s * D_LAT);
        #pragma unroll
        for (int q = 0; q < 8; ++q) {
            const float4 v = vp[q];
            ng[q].x += v.x; ng[q].y += v.y; ng[q].z += v.z; ng[q].w += v.w;
        }
    }

    // combine partner partials -> both lanes hold the full neighbor sum
    float ngs[D_LAT];
    #pragma unroll
    for (int q = 0; q < 8; ++q) {
        ngs[q*4+0] = ng[q].x + __shfl_xor(ng[q].x, 1);
        ngs[q*4+1] = ng[q].y + __shfl_xor(ng[q].y, 1);
        ngs[q*4+2] = ng[q].z + __shfl_xor(ng[q].z, 1);
        ngs[q*4+3] = ng[q].w + __shfl_xor(ng[q].w, 1);
    }

    // own row (read by both lanes; L1/L2-hot)
    float eg[D_LAT];
    {
        const float4* ep = (const float4*)(in + n * D_LAT);
        #pragma unroll
        for (int q = 0; q < 8; ++q) {
            const float4 v = ep[q];
            eg[q*4] = v.x; eg[q*4+1] = v.y; eg[q*4+2] = v.z; eg[q*4+3] = v.w;
        }
    }

    // stage 1: ego @ We + neig @ Wn + B1a (scalar-path weights)
    float acc[D_LAT];
    #pragma unroll
    for (int j = 0; j < D_LAT; ++j) acc[j] = B1a_l[j];
    #pragma unroll 1
    for (int c = 0; c < D_LAT / 8; ++c) {
        #pragma unroll
        for (int kk = 0; kk < 8; ++kk) {
            const int k = c * 8 + kk;
            const float fe = eg[k], fn = ngs[k];
            const float* we = wfold_l + k * D_LAT;                    // uniform
            const float* wn = wfold_l + D_LAT * D_LAT + k * D_LAT;    // uniform
            #pragma unroll
            for (int j = 0; j < D_LAT; ++j)
                acc[j] = fmaf(fe, we[j], fmaf(fn, wn[j], acc[j]));
        }
    }
    #pragma unroll
    for (int j = 0; j < D_LAT; ++j) acc[j] = fmaxf(acc[j], 0.f);

    // stage 2
    float acc2[D_LAT];
    #pragma unroll
    for (int j = 0; j < D_LAT; ++j) acc2[j] = B1b_l[j];
    #pragma unroll 1
    for (int c = 0; c < D_LAT / 8; ++c) {
        #pragma unroll
        for (int kk = 0; kk < 8; ++kk) {
            const float h = acc[c * 8 + kk];
            const float* wr = W1b_l + (c * 8 + kk) * D_LAT;           // uniform
            #pragma unroll
            for (int j = 0; j < D_LAT; ++j)
                acc2[j] = fmaf(h, wr[j], acc2[j]);
        }
    }

    // lane 2n: full ego row; lane 2n+1: full outb RMW row
    if (half == 0) {
        float4* eo = (float4*)(out + n * D_LAT);
        #pragma unroll
        for (int q = 0; q < 8; ++q)
            eo[q] = make_float4(acc2[q*4], acc2[q*4+1], acc2[q*4+2], acc2[q*4+3]);
    } else {
        float4* oo = (float4*)(outb + n * D_LAT);
        #pragma unroll
        for (int q = 0; q < 8; ++q) {
            const float4 prev = oo[q];
            oo[q] = make_float4(fmaf(al, acc2[q*4], prev.x),
                                fmaf(al, acc2[q*4+1], prev.y),
                                fmaf(al, acc2[q*4+2], prev.z),
                                fmaf(al, acc2[q*4+3], prev.w));
        }
    }
}

// ---------------------------------------------------------------------------
// Per-graph top-30 (stable ties -> smaller index) + gather + relu (unchanged)
// ---------------------------------------------------------------------------
__global__ __launch_bounds__(256) void k_topk(
    const float* __restrict__ ego, const float* __restrict__ outb,
    float* __restrict__ y)
{
    __shared__ float vals[512];
    __shared__ int topidx[K_TOP];
    __shared__ float wv[4];
    __shared__ int wi[4];

    const int g = blockIdx.x, t = threadIdx.x;
    for (int i = t; i < 512; i += 256)
        vals[i] = (i < NPG) ? ego[((size_t)g * NPG + i) * D_LAT + (D_LAT - 1)]
                            : -INFINITY;
    __syncthreads();

    for (int k = 0; k < K_TOP; ++k) {
        float v = -INFINITY; int bi = 0x7fffffff;
        for (int i = t; i < NPG; i += 256) {
            const float x = vals[i];
            if (x > v || (x == v && i < bi)) { v = x; bi = i; }
        }
        for (int off = 32; off > 0; off >>= 1) {
            const float ov = __shfl_down(v, off);
            const int   oi = __shfl_down(bi, off);
            if (ov > v || (ov == v && oi < bi)) { v = ov; bi = oi; }
        }
        if ((t & 63) == 0) { wv[t >> 6] = v; wi[t >> 6] = bi; }
        __syncthreads();
        if (t == 0) {
            for (int w = 1; w < 4; ++w)
                if (wv[w] > v || (wv[w] == v && wi[w] < bi)) { v = wv[w]; bi = wi[w]; }
            topidx[k] = bi;
            vals[bi] = -INFINITY;
        }
        __syncthreads();
    }

    for (int j = t; j < K_TOP * D_LAT; j += 256) {
        const int kk = j >> 5, d = j & 31;
        const size_t node = (size_t)g * NPG + topidx[kk];
        y[(size_t)g * (K_TOP * D_LAT) + j] = fmaxf(outb[node * D_LAT + d], 0.f);
    }
}

// ---------------------------------------------------------------------------
extern "C" void kernel_launch(void* const* d_in, const int* in_sizes, int n_in,
                              void* d_out, int out_size, void* d_ws, size_t ws_size,
                              hipStream_t stream)
{
    const float* X    = (const float*)d_in[0];
    const float* alpha= (const float*)d_in[1];
    const float* w0a  = (const float*)d_in[2];
    const float* b0a  = (const float*)d_in[3];
    const float* w0b  = (const float*)d_in[4];
    const float* b0b  = (const float*)d_in[5];
    const float* W1a  = (const float*)d_in[6];
    const float* B1a  = (const float*)d_in[7];
    const float* W1b  = (const float*)d_in[8];
    const float* B1b  = (const float*)d_in[9];
    const int* esrc   = (const int*)d_in[10];
    const int* edst   = (const int*)d_in[11];
    float* y = (float*)d_out;

    float* egoA   = (float*)d_ws;
    float* outb   = egoA + (size_t)N_NODES * D_LAT;
    float* egoB   = outb + (size_t)N_NODES * D_LAT;
    int*   packed = (int*)egoB;                              // alias: dead before layer 0
    int*   off    = (int*)(egoB + (size_t)N_NODES * D_LAT);  // N+1
    int*   srcidx = off + (N_NODES + 1);                     // E
    int*   ghist  = srcidx + E_EDGES;                        // NB
    int*   gbase  = ghist + NB;                              // NB+1
    int*   gcursor= gbase + (NB + 1);                        // NB
    float* wfold  = (float*)(gcursor + NB);                  // 3 * 2048

    k_foldw<<<L_LAYERS, 256, 0, stream>>>(W1a, wfold);

    hipMemsetAsync(ghist, 0, NB * sizeof(int), stream);
    k_bcount  <<<CBLOCKS, 256, 0, stream>>>(edst, ghist);
    k_bscan   <<<1, 1024, 0, stream>>>(ghist, gbase, gcursor);
    k_bscatter<<<CBLOCKS, 256, 0, stream>>>(esrc, edst, gcursor, packed);
    k_bcsr    <<<NB, 256, 0, stream>>>(gbase, packed, off, srcidx);

    k_mlp0<<<N_NODES / 256, 256, 0, stream>>>(X, w0a, b0a, w0b, b0b, alpha, egoA, outb);

    float* cur = egoA;
    float* nxt = egoB;
    for (int l = 0; l < L_LAYERS; ++l) {
        k_layer<<<N_NODES * 2 / 256, 256, 0, stream>>>(
            cur, off, srcidx, wfold + (size_t)l * 2 * D_LAT * D_LAT,
            W1b + (size_t)l * D_LAT * D_LAT, B1a + (size_t)l * D_LAT,
            B1b + (size_t)l * D_LAT, alpha, l, nxt, outb);
        float* tmp = cur; cur = nxt; nxt = tmp;
    }

    // after 3 layers, final ego is in `cur` (== egoB)
    k_topk<<<B_G, 256, 0, stream>>>(cur, outb, y);
}